// Round 9
// baseline (2172.860 us; speedup 1.0000x reference)
//
#include <hip/hip_runtime.h>
#include <hip/hip_bf16.h>
#include <math.h>

// CausalFullAttention: out[b,l,h,d] = softmax_s( 0.125*(q.k + bias[l,s]), s<=l ) @ V
// B=4 L=S=2048 H=8 E=D=64, fp32 in/out, bf16 MFMA compute.
// R8: remove the per-tile vmcnt(0) drain. Raw s_barrier (no implicit waitcnt) +
//     lgkmcnt-only visibility waits; 2-deep staging with two static register sets
//     (A/B) so the LDS-write waits are COUNTED vmcnt (newer prefetch stays in
//     flight). Grid/block/compute structure identical to R7 for attribution.

typedef __bf16 bf16x8 __attribute__((ext_vector_type(8)));
typedef __bf16 bf16x2 __attribute__((ext_vector_type(2)));
typedef float  f32x4  __attribute__((ext_vector_type(4)));

#define NB 4
#define NL 2048
#define NS 2048
#define NH 8
#define NE 64
#define ND 64

__device__ __forceinline__ int swz(int d) { return ((d ^ (d >> 3)) & 7) << 3; }

__device__ __forceinline__ bf16x8 cvt8s(float4 a, float4 b, float sc) {
    bf16x8 r;
    r[0] = (__bf16)(a.x * sc); r[1] = (__bf16)(a.y * sc);
    r[2] = (__bf16)(a.z * sc); r[3] = (__bf16)(a.w * sc);
    r[4] = (__bf16)(b.x * sc); r[5] = (__bf16)(b.y * sc);
    r[6] = (__bf16)(b.z * sc); r[7] = (__bf16)(b.w * sc);
    return r;
}
__device__ __forceinline__ bf16x8 cvt8(float4 a, float4 b) {
    bf16x8 r;
    r[0] = (__bf16)a.x; r[1] = (__bf16)a.y; r[2] = (__bf16)a.z; r[3] = (__bf16)a.w;
    r[4] = (__bf16)b.x; r[5] = (__bf16)b.y; r[6] = (__bf16)b.z; r[7] = (__bf16)b.w;
    return r;
}

__global__ __launch_bounds__(512, 4)
void fa_fwd(const float* __restrict__ Q, const float* __restrict__ K,
            const float* __restrict__ V, const float* __restrict__ Bias,
            float* __restrict__ Out)
{
    __shared__ __bf16 Klds[2][64][72];   // K tile [kv][e], +8 pad
    __shared__ __bf16 Vlds[2][64][64];   // V^T tile [d][kv], XOR swizzle
    __shared__ __bf16 Plds[8][16][72];   // per-wave P bounce

    const int tid  = threadIdx.x;
    const int w    = tid >> 6, lane = tid & 63;
    const int g    = lane >> 4, li = lane & 15;

    // 512 blocks, all resident (2/CU); complementary heavy/light pairing.
    const int id = blockIdx.x;
    int bh, qp_;
    if (id < 256) { bh = id >> 4;                qp_ = 15 - (id & 15); }
    else          { bh = 16 + ((id - 256) >> 4); qp_ = id & 15;        }
    const int b   = bh >> 3, h = bh & 7;
    const int qb  = qp_ << 7;
    const int qw  = qb + (w << 4);        // this wave's first q row

    const float SC = 0.125f * 1.44269504088896340736f;  // scale * log2(e)

    // Q fragments, loaded once, pre-scaled
    bf16x8 qa[2];
    {
        const float* qp = Q + (((size_t)(b * NL + qw + li)) * NH + h) * NE;
        #pragma unroll
        for (int eh = 0; eh < 2; ++eh) {
            const int e0 = eh * 32 + g * 8;
            float4 f0 = *(const float4*)(qp + e0);
            float4 f1 = *(const float4*)(qp + e0 + 4);
            qa[eh] = cvt8s(f0, f1, SC);
        }
    }

    f32x4 o[4] = {};
    float m_run[4] = {-INFINITY, -INFINITY, -INFINITY, -INFINITY};
    float l_run[4] = {};

    const int ntiles = (qb >> 6) + 2;          // kv tiles cover rows 0..qb+127
    const int tdiag  = (qw + 15) >> 6;         // last tile this wave computes

    // cooperative staging indices (512 threads)
    const int skv = tid >> 3,        se0 = (tid & 7) << 3;   // K: row, 8-float chunk
    const int vkv = (tid >> 4) << 1, vd0 = (tid & 15) << 2;  // V: 2kv x 4d sub-block

    const float* kp0 = K + (((size_t)(b * NS + skv)) * NH + h) * NE + se0;
    const float* vp0 = V + (((size_t)(b * NS + vkv)) * NH + h) * ND + vd0;

    // two stage register sets (static, rule #20)
    float4 kA0, kA1, vA0, vA1, kB0, kB1, vB0, vB1;
    float  bA[4][4], bB[4][4];

    auto issue_kvA = [&](int T) {
        const float* kp = kp0 + (size_t)(T << 6) * (NH * NE);
        kA0 = ((const float4*)kp)[0]; kA1 = ((const float4*)kp)[1];
        const float* vp = vp0 + (size_t)(T << 6) * (NH * ND);
        vA0 = *(const float4*)(vp); vA1 = *(const float4*)(vp + NH * ND);
    };
    auto issue_kvB = [&](int T) {
        const float* kp = kp0 + (size_t)(T << 6) * (NH * NE);
        kB0 = ((const float4*)kp)[0]; kB1 = ((const float4*)kp)[1];
        const float* vp = vp0 + (size_t)(T << 6) * (NH * ND);
        vB0 = *(const float4*)(vp); vB1 = *(const float4*)(vp + NH * ND);
    };
    auto issue_bias = [&](float (&bx)[4][4], int T) {
        const int kvn = T << 6;
        #pragma unroll
        for (int j = 0; j < 4; ++j) {
            const float* bp = Bias + (size_t)(qw + g * 4 + j) * NS + kvn + li;
            #pragma unroll
            for (int c = 0; c < 4; ++c) bx[j][c] = bp[c * 16];
        }
    };
    auto write_ldsA = [&](int nxt) {
        *(bf16x8*)&Klds[nxt][skv][se0] = cvt8(kA0, kA1);
        const float* f0 = (const float*)&vA0;
        const float* f1 = (const float*)&vA1;
        #pragma unroll
        for (int dd = 0; dd < 4; ++dd) {
            bf16x2 cc; cc[0] = (__bf16)f0[dd]; cc[1] = (__bf16)f1[dd];
            *(bf16x2*)&Vlds[nxt][vd0 + dd][vkv ^ swz(vd0 + dd)] = cc;
        }
    };
    auto write_ldsB = [&](int nxt) {
        *(bf16x8*)&Klds[nxt][skv][se0] = cvt8(kB0, kB1);
        const float* f0 = (const float*)&vB0;
        const float* f1 = (const float*)&vB1;
        #pragma unroll
        for (int dd = 0; dd < 4; ++dd) {
            bf16x2 cc; cc[0] = (__bf16)f0[dd]; cc[1] = (__bf16)f1[dd];
            *(bf16x2*)&Vlds[nxt][vd0 + dd][vkv ^ swz(vd0 + dd)] = cc;
        }
    };

    auto compute_tile = [&](int t, const float (&bc)[4][4]) {
        const int kv0 = t << 6;
        const int cur = t & 1;
        if (kv0 > qw + 15) return;         // wave-uniform causal skip
        f32x4 s[4];
        #pragma unroll
        for (int c = 0; c < 4; ++c) {
            f32x4 acc = {};
            #pragma unroll
            for (int eh = 0; eh < 2; ++eh) {
                bf16x8 kb = *(const bf16x8*)&Klds[cur][c * 16 + li][eh * 32 + g * 8];
                acc = __builtin_amdgcn_mfma_f32_16x16x32_bf16(qa[eh], kb, acc, 0, 0, 0);
            }
            s[c] = acc;
        }
        if (kv0 + 63 > qw) {               // straddle: bias + causal select
            #pragma unroll
            for (int j = 0; j < 4; ++j) {
                const int lg = qw + g * 4 + j;
                #pragma unroll
                for (int c = 0; c < 4; ++c) {
                    const int sg = kv0 + c * 16 + li;
                    s[c][j] = (sg <= lg) ? fmaf(bc[j][c], SC, s[c][j]) : -INFINITY;
                }
            }
        } else {
            #pragma unroll
            for (int j = 0; j < 4; ++j)
                #pragma unroll
                for (int c = 0; c < 4; ++c)
                    s[c][j] = fmaf(bc[j][c], SC, s[c][j]);
        }
        float pm[4];
        #pragma unroll
        for (int j = 0; j < 4; ++j)
            pm[j] = fmaxf(fmaxf(s[0][j], s[1][j]), fmaxf(s[2][j], s[3][j]));
        #pragma unroll
        for (int off = 1; off < 16; off <<= 1) {
            #pragma unroll
            for (int j = 0; j < 4; ++j)
                pm[j] = fmaxf(pm[j], __shfl_xor(pm[j], off, 64));
        }
        float corr[4];
        #pragma unroll
        for (int j = 0; j < 4; ++j) {
            const float mn = fmaxf(m_run[j], pm[j]);
            corr[j] = exp2f(m_run[j] - mn);
            m_run[j] = mn;
        }
        #pragma unroll
        for (int c = 0; c < 4; ++c)
            #pragma unroll
            for (int j = 0; j < 4; ++j)
                s[c][j] = exp2f(s[c][j] - m_run[j]);
        float rs[4];
        #pragma unroll
        for (int j = 0; j < 4; ++j)
            rs[j] = (s[0][j] + s[1][j]) + (s[2][j] + s[3][j]);
        #pragma unroll
        for (int off = 1; off < 16; off <<= 1) {
            #pragma unroll
            for (int j = 0; j < 4; ++j)
                rs[j] += __shfl_xor(rs[j], off, 64);
        }
        #pragma unroll
        for (int j = 0; j < 4; ++j) {
            l_run[j] = l_run[j] * corr[j] + rs[j];
            o[0][j] *= corr[j]; o[1][j] *= corr[j];
            o[2][j] *= corr[j]; o[3][j] *= corr[j];
        }
        #pragma unroll
        for (int c = 0; c < 4; ++c)
            #pragma unroll
            for (int j = 0; j < 4; ++j)
                Plds[w][g * 4 + j][c * 16 + li] = (__bf16)s[c][j];
        asm volatile("s_waitcnt lgkmcnt(0)" ::: "memory");
        __builtin_amdgcn_sched_barrier(0);
        bf16x8 pa0 = *(const bf16x8*)&Plds[w][li][g * 8];
        bf16x8 pa1 = *(const bf16x8*)&Plds[w][li][g * 8 + 32];
        #pragma unroll
        for (int dt = 0; dt < 4; ++dt) {
            const int d = dt * 16 + li;
            bf16x8 v0 = *(const bf16x8*)&Vlds[cur][d][(g * 8) ^ swz(d)];
            bf16x8 v1 = *(const bf16x8*)&Vlds[cur][d][(32 + g * 8) ^ swz(d)];
            o[dt] = __builtin_amdgcn_mfma_f32_16x16x32_bf16(pa0, v0, o[dt], 0, 0, 0);
            o[dt] = __builtin_amdgcn_mfma_f32_16x16x32_bf16(pa1, v1, o[dt], 0, 0, 0);
        }
    };

    // ---- prologue: tiles 0 (->A) and 1 (->B); write tile 0 to buf0 ----
    issue_kvA(0);
    issue_bias(bA, 0);                      // every wave computes tile 0
    issue_kvB(1);
    if (1 <= tdiag) issue_bias(bB, 1);
    write_ldsA(0);                          // counted vmcnt: waits A, B in flight
    asm volatile("s_waitcnt lgkmcnt(0)" ::: "memory");
    __builtin_amdgcn_s_barrier();

    // ---- main loop: NO vmcnt drains at barriers; 2-deep staging ----
    for (int t = 0; t < ntiles; t += 2) {
        // === tile t (even): bias in bA; issue t+2 into A; write t+1 from B ===
        if (t + 2 < ntiles) issue_kvA(t + 2);
        compute_tile(t, bA);
        if (t + 2 <= tdiag) issue_bias(bA, t + 2);
        asm volatile("" ::: "memory");
        __builtin_amdgcn_s_barrier();       // all waves done reading buf[(t+1)&1]
        if (t + 1 < ntiles) write_ldsB(1);  // counted vmcnt (A's t+2 stays in flight)
        asm volatile("s_waitcnt lgkmcnt(0)" ::: "memory");
        __builtin_amdgcn_s_barrier();       // writes visible

        if (t + 1 < ntiles) {
            // === tile t+1 (odd): bias in bB; issue t+3 into B; write t+2 from A ===
            if (t + 3 < ntiles) issue_kvB(t + 3);
            compute_tile(t + 1, bB);
            if (t + 3 <= tdiag) issue_bias(bB, t + 3);
            asm volatile("" ::: "memory");
            __builtin_amdgcn_s_barrier();
            if (t + 2 < ntiles) write_ldsA(0);
            asm volatile("s_waitcnt lgkmcnt(0)" ::: "memory");
            __builtin_amdgcn_s_barrier();
        }
    }

    // ---- epilogue: normalize and store fp32 ----
    #pragma unroll
    for (int j = 0; j < 4; ++j) {
        const float inv = 1.0f / l_run[j];
        const int lg = qw + g * 4 + j;
        float* op = Out + (((size_t)(b * NL + lg)) * NH + h) * ND + li;
        op[0]  = o[0][j] * inv;
        op[16] = o[1][j] * inv;
        op[32] = o[2][j] * inv;
        op[48] = o[3][j] * inv;
    }
}

extern "C" void kernel_launch(void* const* d_in, const int* in_sizes, int n_in,
                              void* d_out, int out_size, void* d_ws, size_t ws_size,
                              hipStream_t stream)
{
    const float* Q    = (const float*)d_in[0];
    const float* K    = (const float*)d_in[1];
    const float* V    = (const float*)d_in[2];
    const float* Bias = (const float*)d_in[3];
    // d_in[4] (attn_mask) is the static triu(k=1) causal mask - handled analytically.
    float* Out = (float*)d_out;
    dim3 grid(NL / 128 * NB * NH);   // 512 blocks, remapped in-kernel
    dim3 block(512);
    fa_fwd<<<grid, block, 0, stream>>>(Q, K, V, Bias, Out);
}

// Round 10
// 137.683 us; speedup vs baseline: 15.7816x; 15.7816x over previous
//
#include <hip/hip_runtime.h>
#include <hip/hip_bf16.h>
#include <math.h>

// CausalFullAttention: out[b,l,h,d] = softmax_s( 0.125*(q.k + bias[l,s]), s<=l ) @ V
// B=4 L=S=2048 H=8 E=D=64, fp32 in/out, bf16 MFMA compute.
// R9: R8 (no-vmcnt-drain main loop, 2-deep A/B staging, raw s_barrier) with the
//     spill bug fixed: __launch_bounds__(512) only (R8's ",4" capped VGPR at 64
//     -> 7.3GB scratch traffic), and no address-taking of register float4s.

typedef __bf16 bf16x8 __attribute__((ext_vector_type(8)));
typedef __bf16 bf16x2 __attribute__((ext_vector_type(2)));
typedef float  f32x4  __attribute__((ext_vector_type(4)));

#define NB 4
#define NL 2048
#define NS 2048
#define NH 8
#define NE 64
#define ND 64

__device__ __forceinline__ int swz(int d) { return ((d ^ (d >> 3)) & 7) << 3; }

__device__ __forceinline__ bf16x8 cvt8s(float4 a, float4 b, float sc) {
    bf16x8 r;
    r[0] = (__bf16)(a.x * sc); r[1] = (__bf16)(a.y * sc);
    r[2] = (__bf16)(a.z * sc); r[3] = (__bf16)(a.w * sc);
    r[4] = (__bf16)(b.x * sc); r[5] = (__bf16)(b.y * sc);
    r[6] = (__bf16)(b.z * sc); r[7] = (__bf16)(b.w * sc);
    return r;
}
__device__ __forceinline__ bf16x8 cvt8(float4 a, float4 b) {
    bf16x8 r;
    r[0] = (__bf16)a.x; r[1] = (__bf16)a.y; r[2] = (__bf16)a.z; r[3] = (__bf16)a.w;
    r[4] = (__bf16)b.x; r[5] = (__bf16)b.y; r[6] = (__bf16)b.z; r[7] = (__bf16)b.w;
    return r;
}

__global__ __launch_bounds__(512)
void fa_fwd(const float* __restrict__ Q, const float* __restrict__ K,
            const float* __restrict__ V, const float* __restrict__ Bias,
            float* __restrict__ Out)
{
    __shared__ __bf16 Klds[2][64][72];   // K tile [kv][e], +8 pad
    __shared__ __bf16 Vlds[2][64][64];   // V^T tile [d][kv], XOR swizzle
    __shared__ __bf16 Plds[8][16][72];   // per-wave P bounce

    const int tid  = threadIdx.x;
    const int w    = tid >> 6, lane = tid & 63;
    const int g    = lane >> 4, li = lane & 15;

    // 512 blocks, all resident (2/CU); complementary heavy/light pairing.
    const int id = blockIdx.x;
    int bh, qp_;
    if (id < 256) { bh = id >> 4;                qp_ = 15 - (id & 15); }
    else          { bh = 16 + ((id - 256) >> 4); qp_ = id & 15;        }
    const int b   = bh >> 3, h = bh & 7;
    const int qb  = qp_ << 7;
    const int qw  = qb + (w << 4);        // this wave's first q row

    const float SC = 0.125f * 1.44269504088896340736f;  // scale * log2(e)

    // Q fragments, loaded once, pre-scaled
    bf16x8 qa[2];
    {
        const float* qp = Q + (((size_t)(b * NL + qw + li)) * NH + h) * NE;
        #pragma unroll
        for (int eh = 0; eh < 2; ++eh) {
            const int e0 = eh * 32 + g * 8;
            float4 f0 = *(const float4*)(qp + e0);
            float4 f1 = *(const float4*)(qp + e0 + 4);
            qa[eh] = cvt8s(f0, f1, SC);
        }
    }

    f32x4 o[4] = {};
    float m_run[4] = {-INFINITY, -INFINITY, -INFINITY, -INFINITY};
    float l_run[4] = {};

    const int ntiles = (qb >> 6) + 2;          // kv tiles cover rows 0..qb+127
    const int tdiag  = (qw + 15) >> 6;         // last tile this wave computes

    // cooperative staging indices (512 threads)
    const int skv = tid >> 3,        se0 = (tid & 7) << 3;   // K: row, 8-float chunk
    const int vkv = (tid >> 4) << 1, vd0 = (tid & 15) << 2;  // V: 2kv x 4d sub-block

    const float* kp0 = K + (((size_t)(b * NS + skv)) * NH + h) * NE + se0;
    const float* vp0 = V + (((size_t)(b * NS + vkv)) * NH + h) * ND + vd0;

    // two stage register sets (static, rule #20)
    float4 kA0, kA1, vA0, vA1, kB0, kB1, vB0, vB1;
    float  bA[4][4], bB[4][4];

    auto issue_kvA = [&](int T) {
        const float* kp = kp0 + (size_t)(T << 6) * (NH * NE);
        kA0 = ((const float4*)kp)[0]; kA1 = ((const float4*)kp)[1];
        const float* vp = vp0 + (size_t)(T << 6) * (NH * ND);
        vA0 = *(const float4*)(vp); vA1 = *(const float4*)(vp + NH * ND);
    };
    auto issue_kvB = [&](int T) {
        const float* kp = kp0 + (size_t)(T << 6) * (NH * NE);
        kB0 = ((const float4*)kp)[0]; kB1 = ((const float4*)kp)[1];
        const float* vp = vp0 + (size_t)(T << 6) * (NH * ND);
        vB0 = *(const float4*)(vp); vB1 = *(const float4*)(vp + NH * ND);
    };
    auto issue_bias = [&](float (&bx)[4][4], int T) {
        const int kvn = T << 6;
        #pragma unroll
        for (int j = 0; j < 4; ++j) {
            const float* bp = Bias + (size_t)(qw + g * 4 + j) * NS + kvn + li;
            #pragma unroll
            for (int c = 0; c < 4; ++c) bx[j][c] = bp[c * 16];
        }
    };
    auto write_ldsA = [&](int nxt) {
        *(bf16x8*)&Klds[nxt][skv][se0] = cvt8(kA0, kA1);
        bf16x2 cc;
        cc[0]=(__bf16)vA0.x; cc[1]=(__bf16)vA1.x; *(bf16x2*)&Vlds[nxt][vd0+0][vkv ^ swz(vd0+0)] = cc;
        cc[0]=(__bf16)vA0.y; cc[1]=(__bf16)vA1.y; *(bf16x2*)&Vlds[nxt][vd0+1][vkv ^ swz(vd0+1)] = cc;
        cc[0]=(__bf16)vA0.z; cc[1]=(__bf16)vA1.z; *(bf16x2*)&Vlds[nxt][vd0+2][vkv ^ swz(vd0+2)] = cc;
        cc[0]=(__bf16)vA0.w; cc[1]=(__bf16)vA1.w; *(bf16x2*)&Vlds[nxt][vd0+3][vkv ^ swz(vd0+3)] = cc;
    };
    auto write_ldsB = [&](int nxt) {
        *(bf16x8*)&Klds[nxt][skv][se0] = cvt8(kB0, kB1);
        bf16x2 cc;
        cc[0]=(__bf16)vB0.x; cc[1]=(__bf16)vB1.x; *(bf16x2*)&Vlds[nxt][vd0+0][vkv ^ swz(vd0+0)] = cc;
        cc[0]=(__bf16)vB0.y; cc[1]=(__bf16)vB1.y; *(bf16x2*)&Vlds[nxt][vd0+1][vkv ^ swz(vd0+1)] = cc;
        cc[0]=(__bf16)vB0.z; cc[1]=(__bf16)vB1.z; *(bf16x2*)&Vlds[nxt][vd0+2][vkv ^ swz(vd0+2)] = cc;
        cc[0]=(__bf16)vB0.w; cc[1]=(__bf16)vB1.w; *(bf16x2*)&Vlds[nxt][vd0+3][vkv ^ swz(vd0+3)] = cc;
    };

    auto compute_tile = [&](int t, const float (&bc)[4][4]) {
        const int kv0 = t << 6;
        const int cur = t & 1;
        if (kv0 > qw + 15) return;         // wave-uniform causal skip
        f32x4 s[4];
        #pragma unroll
        for (int c = 0; c < 4; ++c) {
            f32x4 acc = {};
            #pragma unroll
            for (int eh = 0; eh < 2; ++eh) {
                bf16x8 kb = *(const bf16x8*)&Klds[cur][c * 16 + li][eh * 32 + g * 8];
                acc = __builtin_amdgcn_mfma_f32_16x16x32_bf16(qa[eh], kb, acc, 0, 0, 0);
            }
            s[c] = acc;
        }
        if (kv0 + 63 > qw) {               // straddle: bias + causal select
            #pragma unroll
            for (int j = 0; j < 4; ++j) {
                const int lg = qw + g * 4 + j;
                #pragma unroll
                for (int c = 0; c < 4; ++c) {
                    const int sg = kv0 + c * 16 + li;
                    s[c][j] = (sg <= lg) ? fmaf(bc[j][c], SC, s[c][j]) : -INFINITY;
                }
            }
        } else {
            #pragma unroll
            for (int j = 0; j < 4; ++j)
                #pragma unroll
                for (int c = 0; c < 4; ++c)
                    s[c][j] = fmaf(bc[j][c], SC, s[c][j]);
        }
        float pm[4];
        #pragma unroll
        for (int j = 0; j < 4; ++j)
            pm[j] = fmaxf(fmaxf(s[0][j], s[1][j]), fmaxf(s[2][j], s[3][j]));
        #pragma unroll
        for (int off = 1; off < 16; off <<= 1) {
            #pragma unroll
            for (int j = 0; j < 4; ++j)
                pm[j] = fmaxf(pm[j], __shfl_xor(pm[j], off, 64));
        }
        float corr[4];
        #pragma unroll
        for (int j = 0; j < 4; ++j) {
            const float mn = fmaxf(m_run[j], pm[j]);
            corr[j] = exp2f(m_run[j] - mn);
            m_run[j] = mn;
        }
        #pragma unroll
        for (int c = 0; c < 4; ++c)
            #pragma unroll
            for (int j = 0; j < 4; ++j)
                s[c][j] = exp2f(s[c][j] - m_run[j]);
        float rs[4];
        #pragma unroll
        for (int j = 0; j < 4; ++j)
            rs[j] = (s[0][j] + s[1][j]) + (s[2][j] + s[3][j]);
        #pragma unroll
        for (int off = 1; off < 16; off <<= 1) {
            #pragma unroll
            for (int j = 0; j < 4; ++j)
                rs[j] += __shfl_xor(rs[j], off, 64);
        }
        #pragma unroll
        for (int j = 0; j < 4; ++j) {
            l_run[j] = l_run[j] * corr[j] + rs[j];
            o[0][j] *= corr[j]; o[1][j] *= corr[j];
            o[2][j] *= corr[j]; o[3][j] *= corr[j];
        }
        #pragma unroll
        for (int c = 0; c < 4; ++c)
            #pragma unroll
            for (int j = 0; j < 4; ++j)
                Plds[w][g * 4 + j][c * 16 + li] = (__bf16)s[c][j];
        asm volatile("s_waitcnt lgkmcnt(0)" ::: "memory");
        __builtin_amdgcn_sched_barrier(0);
        bf16x8 pa0 = *(const bf16x8*)&Plds[w][li][g * 8];
        bf16x8 pa1 = *(const bf16x8*)&Plds[w][li][g * 8 + 32];
        #pragma unroll
        for (int dt = 0; dt < 4; ++dt) {
            const int d = dt * 16 + li;
            bf16x8 v0 = *(const bf16x8*)&Vlds[cur][d][(g * 8) ^ swz(d)];
            bf16x8 v1 = *(const bf16x8*)&Vlds[cur][d][(32 + g * 8) ^ swz(d)];
            o[dt] = __builtin_amdgcn_mfma_f32_16x16x32_bf16(pa0, v0, o[dt], 0, 0, 0);
            o[dt] = __builtin_amdgcn_mfma_f32_16x16x32_bf16(pa1, v1, o[dt], 0, 0, 0);
        }
    };

    // ---- prologue: tiles 0 (->A) and 1 (->B); write tile 0 to buf0 ----
    issue_kvA(0);
    issue_bias(bA, 0);                      // every wave computes tile 0
    issue_kvB(1);
    if (1 <= tdiag) issue_bias(bB, 1);
    write_ldsA(0);                          // counted vmcnt: waits A, B in flight
    asm volatile("s_waitcnt lgkmcnt(0)" ::: "memory");
    __builtin_amdgcn_s_barrier();

    // ---- main loop: NO vmcnt drains at barriers; 2-deep staging ----
    for (int t = 0; t < ntiles; t += 2) {
        // === tile t (even): bias in bA; issue t+2 into A; write t+1 from B ===
        if (t + 2 < ntiles) issue_kvA(t + 2);
        compute_tile(t, bA);
        if (t + 2 <= tdiag) issue_bias(bA, t + 2);
        asm volatile("" ::: "memory");
        __builtin_amdgcn_s_barrier();       // all waves done reading buf[(t+1)&1]
        if (t + 1 < ntiles) write_ldsB(1);  // counted vmcnt (A's t+2 stays in flight)
        asm volatile("s_waitcnt lgkmcnt(0)" ::: "memory");
        __builtin_amdgcn_s_barrier();       // writes visible

        if (t + 1 < ntiles) {
            // === tile t+1 (odd): bias in bB; issue t+3 into B; write t+2 from A ===
            if (t + 3 < ntiles) issue_kvB(t + 3);
            compute_tile(t + 1, bB);
            if (t + 3 <= tdiag) issue_bias(bB, t + 3);
            asm volatile("" ::: "memory");
            __builtin_amdgcn_s_barrier();
            if (t + 2 < ntiles) write_ldsA(0);
            asm volatile("s_waitcnt lgkmcnt(0)" ::: "memory");
            __builtin_amdgcn_s_barrier();
        }
    }

    // ---- epilogue: normalize and store fp32 ----
    #pragma unroll
    for (int j = 0; j < 4; ++j) {
        const float inv = 1.0f / l_run[j];
        const int lg = qw + g * 4 + j;
        float* op = Out + (((size_t)(b * NL + lg)) * NH + h) * ND + li;
        op[0]  = o[0][j] * inv;
        op[16] = o[1][j] * inv;
        op[32] = o[2][j] * inv;
        op[48] = o[3][j] * inv;
    }
}

extern "C" void kernel_launch(void* const* d_in, const int* in_sizes, int n_in,
                              void* d_out, int out_size, void* d_ws, size_t ws_size,
                              hipStream_t stream)
{
    const float* Q    = (const float*)d_in[0];
    const float* K    = (const float*)d_in[1];
    const float* V    = (const float*)d_in[2];
    const float* Bias = (const float*)d_in[3];
    // d_in[4] (attn_mask) is the static triu(k=1) causal mask - handled analytically.
    float* Out = (float*)d_out;
    dim3 grid(NL / 128 * NB * NH);   // 512 blocks, remapped in-kernel
    dim3 block(512);
    fa_fwd<<<grid, block, 0, stream>>>(Q, K, V, Bias, Out);
}

// Round 11
// 107.090 us; speedup vs baseline: 20.2900x; 1.2857x over previous
//
#include <hip/hip_runtime.h>
#include <hip/hip_bf16.h>
#include <math.h>

// CausalFullAttention: out[b,l,h,d] = softmax_s( 0.125*(q.k + bias[l,s]), s<=l ) @ V
// B=4 L=S=2048 H=8 E=D=64, fp32 in/out, bf16 MFMA compute.
// R10: swapped-QK^T in-register softmax (T12-style). mfma(K,Q) puts each q-row's
//      scores lane-local (q=li): 15 in-lane ops + 2 shuffles per row-stat (was 4-step
//      chains x4 rows), per-lane scalar m/l, defer-max (THR=8), and the P->LDS bounce
//      replaced by cvt_pk + 16 ds_bpermute re-fragmentation. Shell/grid = R7.

typedef __bf16 bf16x8 __attribute__((ext_vector_type(8)));
typedef __bf16 bf16x2 __attribute__((ext_vector_type(2)));
typedef float  f32x4  __attribute__((ext_vector_type(4)));
typedef unsigned int u32;
typedef u32 u32x4 __attribute__((ext_vector_type(4)));

#define NB 4
#define NL 2048
#define NS 2048
#define NH 8
#define NE 64
#define ND 64

__device__ __forceinline__ int swz(int d) { return ((d ^ (d >> 3)) & 7) << 3; }

__device__ __forceinline__ u32 cvtpk(float lo, float hi) {
    u32 r;
    asm("v_cvt_pk_bf16_f32 %0, %1, %2" : "=v"(r) : "v"(lo), "v"(hi));
    return r;   // D[15:0]=bf16(lo), D[31:16]=bf16(hi)
}
__device__ __forceinline__ float bpermf(int srclane, float v) {
    return __uint_as_float((u32)__builtin_amdgcn_ds_bpermute(srclane << 2, (int)__float_as_uint(v)));
}
__device__ __forceinline__ u32 bpermu(int srclane, u32 v) {
    return (u32)__builtin_amdgcn_ds_bpermute(srclane << 2, (int)v);
}

__device__ __forceinline__ bf16x8 cvt8s(f32x4 a, f32x4 b, float sc) {
    bf16x8 r;
    r[0]=(__bf16)(a[0]*sc); r[1]=(__bf16)(a[1]*sc); r[2]=(__bf16)(a[2]*sc); r[3]=(__bf16)(a[3]*sc);
    r[4]=(__bf16)(b[0]*sc); r[5]=(__bf16)(b[1]*sc); r[6]=(__bf16)(b[2]*sc); r[7]=(__bf16)(b[3]*sc);
    return r;
}
__device__ __forceinline__ bf16x8 cvt8(f32x4 a, f32x4 b) {
    bf16x8 r;
    r[0]=(__bf16)a[0]; r[1]=(__bf16)a[1]; r[2]=(__bf16)a[2]; r[3]=(__bf16)a[3];
    r[4]=(__bf16)b[0]; r[5]=(__bf16)b[1]; r[6]=(__bf16)b[2]; r[7]=(__bf16)b[3];
    return r;
}

__global__ __launch_bounds__(512)
void fa_fwd(const float* __restrict__ Q, const float* __restrict__ K,
            const float* __restrict__ V, const float* __restrict__ Bias,
            float* __restrict__ Out)
{
    __shared__ __bf16 Klds[2][64][72];   // K tile [kv][e], +8 pad
    __shared__ __bf16 Vlds[2][64][64];   // V^T tile [d][kv], XOR swizzle
    // (no Plds: P stays in registers)

    const int tid  = threadIdx.x;
    const int w    = tid >> 6, lane = tid & 63;
    const int g    = lane >> 4, li = lane & 15;

    // 512 blocks, all resident (2/CU); complementary heavy/light pairing.
    const int id = blockIdx.x;
    int bh, qp_;
    if (id < 256) { bh = id >> 4;                qp_ = 15 - (id & 15); }
    else          { bh = 16 + ((id - 256) >> 4); qp_ = id & 15;        }
    const int b   = bh >> 3, h = bh & 7;
    const int qb  = qp_ << 7;
    const int qw  = qb + (w << 4);        // this wave's first q row

    const float SC = 0.125f * 1.44269504088896340736f;  // scale * log2(e)

    // Q fragments (used as the B operand of the swapped QK^T), pre-scaled
    bf16x8 qa[2];
    {
        const float* qp = Q + (((size_t)(b * NL + qw + li)) * NH + h) * NE;
        #pragma unroll
        for (int eh = 0; eh < 2; ++eh) {
            const int e0 = eh * 32 + g * 8;
            f32x4 f0 = *(const f32x4*)(qp + e0);
            f32x4 f1 = *(const f32x4*)(qp + e0 + 4);
            qa[eh] = cvt8s(f0, f1, SC);
        }
    }

    f32x4 o[4] = {};                       // O: row q = g*4+j, col d = dt*16+li
    float m_run = -INFINITY;               // per-lane: row q = qw + li
    float l_run = 0.0f;

    const int ntiles = (qb >> 6) + 2;      // kv tiles cover rows 0..qb+127

    // cooperative staging indices (512 threads)
    const int skv = tid >> 3,        se0 = (tid & 7) << 3;   // K: row, 8-float chunk
    const int vkv = (tid >> 4) << 1, vd0 = (tid & 15) << 2;  // V: 2kv x 4d sub-block

    const float* kp0 = K + (((size_t)(b * NS + skv)) * NH + h) * NE + se0;
    const float* vp0 = V + (((size_t)(b * NS + vkv)) * NH + h) * ND + vd0;
    const float* bp0 = Bias + (size_t)(qw + li) * NS + g * 4;  // per-lane bias row

    f32x4 ka0, ka1, va0, va1;              // stage regs (tile in flight)
    f32x4 bc[4], bn[4];                    // bias regs: [c] -> cols c*16+g*4..+3

    auto write_lds = [&](int buf) {
        *(bf16x8*)&Klds[buf][skv][se0] = cvt8(ka0, ka1);
        #pragma unroll
        for (int dd = 0; dd < 4; ++dd) {
            bf16x2 cc; cc[0] = (__bf16)va0[dd]; cc[1] = (__bf16)va1[dd];
            *(bf16x2*)&Vlds[buf][vd0 + dd][vkv ^ swz(vd0 + dd)] = cc;
        }
    };

    // ---- prologue: tile 0 ----
    ka0 = ((const f32x4*)kp0)[0]; ka1 = ((const f32x4*)kp0)[1];
    va0 = *(const f32x4*)(vp0);   va1 = *(const f32x4*)(vp0 + NH * ND);
    #pragma unroll
    for (int c = 0; c < 4; ++c) bc[c] = *(const f32x4*)(bp0 + c * 16);
    write_lds(0);
    __syncthreads();

    for (int t = 0; t < ntiles; ++t) {
        const int cur = t & 1;
        const bool more = (t + 1 < ntiles);

        // ---- phase A: issue next tile's global loads ----
        if (more) {
            const int kvn = (t + 1) << 6;
            const float* kp = kp0 + (size_t)kvn * (NH * NE);
            ka0 = ((const f32x4*)kp)[0]; ka1 = ((const f32x4*)kp)[1];
            const float* vp = vp0 + (size_t)kvn * (NH * ND);
            va0 = *(const f32x4*)(vp);   va1 = *(const f32x4*)(vp + NH * ND);
            #pragma unroll
            for (int c = 0; c < 4; ++c) bn[c] = *(const f32x4*)(bp0 + kvn + c * 16);
        }

        // ---- phase B: compute tile t (wave-uniform causal skip) ----
        const int kv0 = t << 6;
        if (kv0 <= qw + 15) {
            // swapped QK^T: S[kv][q], lane holds s[c][r] = S[c*16+g*4+r][q=li]
            f32x4 s[4];
            #pragma unroll
            for (int c = 0; c < 4; ++c) {
                f32x4 acc = {};
                #pragma unroll
                for (int eh = 0; eh < 2; ++eh) {
                    bf16x8 kb = *(const bf16x8*)&Klds[cur][c * 16 + li][eh * 32 + g * 8];
                    acc = __builtin_amdgcn_mfma_f32_16x16x32_bf16(kb, qa[eh], acc, 0, 0, 0);
                }
                s[c] = acc;
            }
            const int lg = qw + li;
            if (kv0 + 63 > qw) {           // straddle: bias + causal select
                #pragma unroll
                for (int c = 0; c < 4; ++c)
                    #pragma unroll
                    for (int r = 0; r < 4; ++r) {
                        const int sg = kv0 + c * 16 + g * 4 + r;
                        s[c][r] = (sg <= lg) ? fmaf(bc[c][r], SC, s[c][r]) : -INFINITY;
                    }
            } else {
                #pragma unroll
                for (int c = 0; c < 4; ++c)
                    #pragma unroll
                    for (int r = 0; r < 4; ++r)
                        s[c][r] = fmaf(bc[c][r], SC, s[c][r]);
            }
            // row max: 15 in-lane + 2 shuffles (lanes li,li^16,li^32,li^48 share a row)
            float pm = fmaxf(
                fmaxf(fmaxf(fmaxf(s[0][0],s[0][1]),fmaxf(s[0][2],s[0][3])),
                      fmaxf(fmaxf(s[1][0],s[1][1]),fmaxf(s[1][2],s[1][3]))),
                fmaxf(fmaxf(fmaxf(s[2][0],s[2][1]),fmaxf(s[2][2],s[2][3])),
                      fmaxf(fmaxf(s[3][0],s[3][1]),fmaxf(s[3][2],s[3][3]))));
            pm = fmaxf(pm, __shfl_xor(pm, 16, 64));
            pm = fmaxf(pm, __shfl_xor(pm, 32, 64));
            // defer-max (T13): skip O-rescale when max growth <= 8 in log2 domain
            if (!__all(pm <= m_run + 8.0f)) {
                const float mn = fmaxf(m_run, pm);
                const float corr = exp2f(m_run - mn);
                m_run = mn;
                l_run *= corr;
                #pragma unroll
                for (int j = 0; j < 4; ++j) {   // transport corr to O layout (q=g*4+j)
                    const float cj = bpermf(g * 20 + j, corr);
                    o[0][j] *= cj; o[1][j] *= cj; o[2][j] *= cj; o[3][j] *= cj;
                }
            }
            #pragma unroll
            for (int c = 0; c < 4; ++c)
                #pragma unroll
                for (int r = 0; r < 4; ++r)
                    s[c][r] = exp2f(s[c][r] - m_run);
            float rs = ((s[0][0]+s[0][1])+(s[0][2]+s[0][3]))
                     + ((s[1][0]+s[1][1])+(s[1][2]+s[1][3]))
                     + ((s[2][0]+s[2][1])+(s[2][2]+s[2][3]))
                     + ((s[3][0]+s[3][1])+(s[3][2]+s[3][3]));
            rs += __shfl_xor(rs, 16, 64);
            rs += __shfl_xor(rs, 32, 64);
            l_run += rs;
            // P -> bf16 (cvt_pk) + re-fragmentation into PV A-frags via bpermute.
            // Need: pa[ct] word j2 = P pair kv={ct*32+g*8+2*j2, +1} from lane
            // g'=(2g+(j2>>1))&3, register w[2*ct+(g>=2)][j2&1].
            const u32 w00 = cvtpk(s[0][0], s[0][1]), w01 = cvtpk(s[0][2], s[0][3]);
            const u32 w10 = cvtpk(s[1][0], s[1][1]), w11 = cvtpk(s[1][2], s[1][3]);
            const u32 w20 = cvtpk(s[2][0], s[2][1]), w21 = cvtpk(s[2][2], s[2][3]);
            const u32 w30 = cvtpk(s[3][0], s[3][1]), w31 = cvtpk(s[3][2], s[3][3]);
            const int slA = (((2 * g) & 3) << 4) | li;
            const int slB = (((2 * g + 1) & 3) << 4) | li;
            const bool hi = (g >= 2);
            u32x4 pw0, pw1;
            {
                const u32 tA0a = bpermu(slA, w00), tA0b = bpermu(slA, w10);
                const u32 tA1a = bpermu(slA, w01), tA1b = bpermu(slA, w11);
                const u32 tB0a = bpermu(slB, w00), tB0b = bpermu(slB, w10);
                const u32 tB1a = bpermu(slB, w01), tB1b = bpermu(slB, w11);
                pw0[0] = hi ? tA0b : tA0a;
                pw0[1] = hi ? tA1b : tA1a;
                pw0[2] = hi ? tB0b : tB0a;
                pw0[3] = hi ? tB1b : tB1a;
                const u32 uA0a = bpermu(slA, w20), uA0b = bpermu(slA, w30);
                const u32 uA1a = bpermu(slA, w21), uA1b = bpermu(slA, w31);
                const u32 uB0a = bpermu(slB, w20), uB0b = bpermu(slB, w30);
                const u32 uB1a = bpermu(slB, w21), uB1b = bpermu(slB, w31);
                pw1[0] = hi ? uA0b : uA0a;
                pw1[1] = hi ? uA1b : uA1a;
                pw1[2] = hi ? uB0b : uB0a;
                pw1[3] = hi ? uB1b : uB1a;
            }
            const bf16x8 pa0 = __builtin_bit_cast(bf16x8, pw0);
            const bf16x8 pa1 = __builtin_bit_cast(bf16x8, pw1);
            // PV: O += P @ V (unchanged)
            #pragma unroll
            for (int dt = 0; dt < 4; ++dt) {
                const int d = dt * 16 + li;
                bf16x8 v0 = *(const bf16x8*)&Vlds[cur][d][(g * 8) ^ swz(d)];
                bf16x8 v1 = *(const bf16x8*)&Vlds[cur][d][(32 + g * 8) ^ swz(d)];
                o[dt] = __builtin_amdgcn_mfma_f32_16x16x32_bf16(pa0, v0, o[dt], 0, 0, 0);
                o[dt] = __builtin_amdgcn_mfma_f32_16x16x32_bf16(pa1, v1, o[dt], 0, 0, 0);
            }
        }

        // ---- phase C/D: write next tile into the other buffer ----
        if (more) {
            __syncthreads();
            write_lds(cur ^ 1);
            __syncthreads();
            #pragma unroll
            for (int c = 0; c < 4; ++c) bc[c] = bn[c];
        }
    }

    // ---- epilogue: transport l to O layout, normalize, store fp32 ----
    #pragma unroll
    for (int j = 0; j < 4; ++j) {
        const float lj = bpermf(g * 20 + j, l_run);   // src lane (g, li=g*4+j)
        const float inv = 1.0f / lj;
        const int lgq = qw + g * 4 + j;
        float* op = Out + (((size_t)(b * NL + lgq)) * NH + h) * ND + li;
        op[0]  = o[0][j] * inv;
        op[16] = o[1][j] * inv;
        op[32] = o[2][j] * inv;
        op[48] = o[3][j] * inv;
    }
}

extern "C" void kernel_launch(void* const* d_in, const int* in_sizes, int n_in,
                              void* d_out, int out_size, void* d_ws, size_t ws_size,
                              hipStream_t stream)
{
    const float* Q    = (const float*)d_in[0];
    const float* K    = (const float*)d_in[1];
    const float* V    = (const float*)d_in[2];
    const float* Bias = (const float*)d_in[3];
    // d_in[4] (attn_mask) is the static triu(k=1) causal mask - handled analytically.
    float* Out = (float*)d_out;
    dim3 grid(NL / 128 * NB * NH);   // 512 blocks, remapped in-kernel
    dim3 block(512);
    fa_fwd<<<grid, block, 0, stream>>>(Q, K, V, Bias, Out);
}